// Round 4
// baseline (264.038 us; speedup 1.0000x reference)
//
#include <hip/hip_runtime.h>

// B=8, N=196, C=512, NC=10, H=8, HD=64, SCALE=0.125
//
// Pipeline (all matmuls bf16 MFMA 16x16x32, fp32 accum):
//   pre:      x,anchors -> bf16;  Wqk,Wqk2,Wv,Wproj -> bf16 TRANSPOSED [n][k]
//   proj5:    xq,xq2,xv (1568x512), aq,aq2 (1960x512) bf16
//   fused:    per (b,c,h) block:
//               phase1: RV[jt] = (relu(+S*k2@q2^T) @ v)^T  kept in LDS (36KB)
//               phase2: left = relu(-S*q@k^T) -> d_out (fp32, masked)
//                       out1 += w[b,h,c] * left @ RV   via fp32 atomicAdd
//   final:    out = out1 @ Wproj + bproj (f32)
//
// ws layout (bytes), total 17,752,064:
#define OFF_XB     0u          // x bf16        1,605,632
#define OFF_AB     1605632u    // anchors bf16  2,007,040
#define OFF_WQKT   3612672u    // 512x512 bf16 T  524,288
#define OFF_WQK2T  4136960u
#define OFF_WVT    4661248u
#define OFF_WPROJT 5185536u
#define OFF_XQ     5709824u    // 1,605,632
#define OFF_XQ2    7315456u
#define OFF_XV     8921088u
#define OFF_AQ     10526720u   // 2,007,040
#define OFF_AQ2    12533760u   // 2,007,040
#define OFF_OUT1   14540800u   // 1568*512 f32 = 3,211,264 (memset to 0 each launch)

typedef __attribute__((ext_vector_type(8))) short bf16x8;
typedef __attribute__((ext_vector_type(4))) float f32x4;
#define MFMA(a, b, c) __builtin_amdgcn_mfma_f32_16x16x32_bf16((a), (b), (c), 0, 0, 0)

__device__ __forceinline__ unsigned short f2bf(float x) {
  unsigned u = __builtin_bit_cast(unsigned, x);
  u += 0x7fffu + ((u >> 16) & 1u);
  return (unsigned short)(u >> 16);
}

__device__ __forceinline__ void gl_lds16(const void* g, void* l) {
  __builtin_amdgcn_global_load_lds(
      (const __attribute__((address_space(1))) unsigned int*)g,
      (__attribute__((address_space(3))) unsigned int*)l, 16, 0, 0);
}

// DMA-stage a 64x64 bf16 tile (row stride `stride` shorts) into LDS [64][72].
// Row = 144B = 9 x 16B chunks; chunk 8 loads 16B of source cols 64..71 into the
// pad (never read as data). Rows >= nrows skipped (stale LDS left in place).
__device__ __forceinline__ void stage64(const unsigned short* g0, int stride,
                                        unsigned short (*T)[72], int tid, int nrows) {
  int wv = tid >> 6;
  char* base = (char*)&T[0][0];
#pragma unroll
  for (int i = 0; i < 2; i++) {
    int k = i * 256 + tid;
    int r = k / 9, c = k - r * 9;
    if (r < nrows)
      gl_lds16(g0 + (size_t)r * stride + (c << 3), base + (((i << 2) + wv) << 10));
  }
  if (tid < 64) {
    int k = 512 + tid;
    int r = k / 9, c = k - r * 9;
    if (r < nrows)
      gl_lds16(g0 + (size_t)r * stride + (c << 3), base + 8192);
  }
}

// VGPR-roundtrip tile load with ZERO padding for rows >= nrows.
__device__ __forceinline__ void load_bf16_tile(unsigned short T[64][72], const unsigned short* __restrict__ g,
                                               int row0, int nrows, int col0, int tid) {
  int r = tid >> 2;
  int c0 = (tid & 3) << 4;
  uint4 a = make_uint4(0, 0, 0, 0), b = make_uint4(0, 0, 0, 0);
  if (r < nrows) {
    const unsigned short* p = g + (size_t)(row0 + r) * 512 + col0 + c0;
    a = *(const uint4*)p;
    b = *(const uint4*)(p + 8);
  }
  *(uint4*)&T[r][c0] = a;
  *(uint4*)&T[r][c0 + 8] = b;
}

// Transposed tile load (for V): T[d][j], ZERO for j >= nrows.
__device__ __forceinline__ void load_bf16_tile_T(unsigned short T[64][72], const unsigned short* __restrict__ g,
                                                 int row0, int nrows, int col0, int tid) {
#pragma unroll
  for (int rep = 0; rep < 2; rep++) {
    int j = (tid >> 3) + (rep << 5);
    int d0 = (tid & 7) << 3;
    uint4 a = make_uint4(0, 0, 0, 0);
    if (j < nrows) a = *(const uint4*)(g + (size_t)(row0 + j) * 512 + col0 + d0);
    unsigned short s[8];
    *(uint4*)s = a;
#pragma unroll
    for (int u = 0; u < 8; u++) T[d0 + u][j] = s[u];
  }
}

// ---- pre: bf16 conversions + W transposes ----
__global__ __launch_bounds__(256) void pre_kernel(const float* __restrict__ x, const float* __restrict__ anchors,
                                                  const float* __restrict__ Wqk, const float* __restrict__ Wqk2,
                                                  const float* __restrict__ Wv, const float* __restrict__ Wproj,
                                                  char* __restrict__ ws) {
  int tid = threadIdx.x;
  if (blockIdx.x < 1764) {  // convert x (802816) + anchors (1003520) -> XB/AB (contiguous)
    int base = blockIdx.x * 1024 + (tid << 2);
    float4 f = (base < 802816) ? *(const float4*)(x + base)
                               : *(const float4*)(anchors + (base - 802816));
    unsigned short s[4] = {f2bf(f.x), f2bf(f.y), f2bf(f.z), f2bf(f.w)};
    *(uint2*)((unsigned short*)(ws + OFF_XB) + base) = *(uint2*)s;
    return;
  }
  __shared__ unsigned short Ls[64][72];
  int idx = blockIdx.x - 1764;
  int wsel = idx >> 6, t = idx & 63;
  int k0 = (t >> 3) << 6, n0 = (t & 7) << 6;
  const float* W;
  unsigned short* WT;
  switch (wsel) {
    case 0:  W = Wqk;   WT = (unsigned short*)(ws + OFF_WQKT);   break;
    case 1:  W = Wqk2;  WT = (unsigned short*)(ws + OFF_WQK2T);  break;
    case 2:  W = Wv;    WT = (unsigned short*)(ws + OFF_WVT);    break;
    default: W = Wproj; WT = (unsigned short*)(ws + OFF_WPROJT); break;
  }
  {
    int r = tid >> 2, seg = (tid & 3) << 4;
    const float* p = W + (size_t)(k0 + r) * 512 + n0 + seg;
    float4 f0 = *(const float4*)p, f1 = *(const float4*)(p + 4);
    float4 f2 = *(const float4*)(p + 8), f3 = *(const float4*)(p + 12);
    unsigned short s[16] = {f2bf(f0.x), f2bf(f0.y), f2bf(f0.z), f2bf(f0.w),
                            f2bf(f1.x), f2bf(f1.y), f2bf(f1.z), f2bf(f1.w),
                            f2bf(f2.x), f2bf(f2.y), f2bf(f2.z), f2bf(f2.w),
                            f2bf(f3.x), f2bf(f3.y), f2bf(f3.z), f2bf(f3.w)};
    *(uint4*)&Ls[r][seg] = *(uint4*)s;
    *(uint4*)&Ls[r][seg + 8] = *(uint4*)(s + 8);
  }
  __syncthreads();
  {
    int r = tid >> 2, seg = (tid & 3) << 4;
    unsigned short s[16];
#pragma unroll
    for (int u = 0; u < 16; u++) s[u] = Ls[seg + u][r];
    unsigned short* dst = WT + (size_t)(n0 + r) * 512 + k0 + seg;
    *(uint4*)dst = *(uint4*)s;
    *(uint4*)(dst + 8) = *(uint4*)(s + 8);
  }
}

// ---- pure-bf16 GEMM: out[M,512] = A[M,512] @ WT^T -> bf16 ----
__global__ __launch_bounds__(256) void proj5(char* __restrict__ ws) {
  const unsigned short* xb = (const unsigned short*)(ws + OFF_XB);
  const unsigned short* ab = (const unsigned short*)(ws + OFF_AB);
  const unsigned short* A; const unsigned short* WT; unsigned short* O; int M;
  switch (blockIdx.z) {
    case 0:  A = xb; WT = (unsigned short*)(ws + OFF_WQKT);  O = (unsigned short*)(ws + OFF_XQ);  M = 1568; break;
    case 1:  A = xb; WT = (unsigned short*)(ws + OFF_WQK2T); O = (unsigned short*)(ws + OFF_XQ2); M = 1568; break;
    case 2:  A = xb; WT = (unsigned short*)(ws + OFF_WVT);   O = (unsigned short*)(ws + OFF_XV);  M = 1568; break;
    case 3:  A = ab; WT = (unsigned short*)(ws + OFF_WQKT);  O = (unsigned short*)(ws + OFF_AQ);  M = 1960; break;
    default: A = ab; WT = (unsigned short*)(ws + OFF_WQK2T); O = (unsigned short*)(ws + OFF_AQ2); M = 1960; break;
  }
  __shared__ unsigned short As[64][72];
  __shared__ unsigned short Ws[64][72];
  int row0 = blockIdx.x << 6;
  if (row0 >= M) return;
  int col0 = blockIdx.y << 6;
  int tid = threadIdx.x;
  int w = tid >> 6, lm = tid & 15, lq = (tid >> 4) & 3;
  f32x4 acc[4] = {};
  for (int k0 = 0; k0 < 512; k0 += 64) {
    __syncthreads();
    stage64(A + (size_t)row0 * 512 + k0, 512, As, tid, 64);   // tail rows garbage, masked at store
    stage64(WT + (size_t)col0 * 512 + k0, 512, Ws, tid, 64);
    __syncthreads();
#pragma unroll
    for (int kk = 0; kk < 2; kk++) {
      bf16x8 bf = *(const bf16x8*)&Ws[(w << 4) + lm][(kk << 5) + (lq << 3)];
#pragma unroll
      for (int mi = 0; mi < 4; mi++) {
        bf16x8 af = *(const bf16x8*)&As[(mi << 4) + lm][(kk << 5) + (lq << 3)];
        acc[mi] = MFMA(af, bf, acc[mi]);
      }
    }
  }
  int ncol = col0 + (w << 4) + lm;
#pragma unroll
  for (int mi = 0; mi < 4; mi++)
#pragma unroll
    for (int r2 = 0; r2 < 4; r2++) {
      int row = row0 + (mi << 4) + (lq << 2) + r2;
      if (row < M) O[(size_t)row * 512 + ncol] = f2bf(acc[mi][r2]);
    }
}

// ---- fused rv + attn, one block per (b,c,h) ----
__global__ __launch_bounds__(256) void fused_attn(char* __restrict__ ws, const float* __restrict__ weights,
                                                  float* __restrict__ left, float* __restrict__ out1) {
  const unsigned short* xq  = (const unsigned short*)(ws + OFF_XQ);
  const unsigned short* xq2 = (const unsigned short*)(ws + OFF_XQ2);
  const unsigned short* xv  = (const unsigned short*)(ws + OFF_XV);
  const unsigned short* aq  = (const unsigned short*)(ws + OFF_AQ);
  const unsigned short* aq2 = (const unsigned short*)(ws + OFF_AQ2);
  __shared__ unsigned short RV[4][64][72];  // RV[jt][dd][j_local], 36,864 B
  __shared__ unsigned short Qs[64][72];
  __shared__ unsigned short Ks[64][72];
  __shared__ unsigned short Vt[64][72];
  __shared__ unsigned short Ss[64][72];
  int bch = blockIdx.x;
  int h = bch & 7, bc = bch >> 3;
  int c = bc % 10, b = bc / 10;
  int bh = b * 8 + h;
  int tid = threadIdx.x;
  int w = tid >> 6, lm = tid & 15, lq = (tid >> 4) & 3;
  float wc = weights[bh * 10 + c];

  // ---- phase 1: RV[it] = (relu(0.125 * k2_tile @ q2^T) @ v)^T, anchors-i padded to 0
  for (int it = 0; it < 4; it++) {
    int i0 = it << 6;
    int ni = min(64, 196 - i0);
    load_bf16_tile(Ks, aq2, c * 196 + i0, ni, h << 6, tid);  // zero-padded rows (REQUIRED)
    __syncthreads();
    bf16x8 kf[4][2];
#pragma unroll
    for (int mi = 0; mi < 4; mi++)
#pragma unroll
      for (int kk = 0; kk < 2; kk++)
        kf[mi][kk] = *(const bf16x8*)&Ks[(mi << 4) + lm][(kk << 5) + (lq << 3)];
    f32x4 acc[4] = {};
    for (int jt = 0; jt < 4; jt++) {
      int j0 = jt << 6;
      int nj = min(64, 196 - j0);
      __syncthreads();
      stage64(xq2 + (size_t)(b * 196 + j0) * 512 + (h << 6), 512, Qs, tid, 64);  // garbage tail ok (Vt=0)
      load_bf16_tile_T(Vt, xv, b * 196 + j0, nj, h << 6, tid);
      __syncthreads();
      f32x4 s[4] = {};
#pragma unroll
      for (int kk = 0; kk < 2; kk++) {
        bf16x8 bf = *(const bf16x8*)&Qs[(w << 4) + lm][(kk << 5) + (lq << 3)];
#pragma unroll
        for (int mi = 0; mi < 4; mi++) s[mi] = MFMA(kf[mi][kk], bf, s[mi]);
      }
#pragma unroll
      for (int mi = 0; mi < 4; mi++)
#pragma unroll
        for (int r = 0; r < 4; r++)
          Ss[(mi << 4) + (lq << 2) + r][(w << 4) + lm] = f2bf(fmaxf(0.125f * s[mi][r], 0.f));
      __syncthreads();
#pragma unroll
      for (int kk = 0; kk < 2; kk++) {
        bf16x8 bf = *(const bf16x8*)&Vt[(w << 4) + lm][(kk << 5) + (lq << 3)];
#pragma unroll
        for (int mi = 0; mi < 4; mi++) {
          bf16x8 af = *(const bf16x8*)&Ss[(mi << 4) + lm][(kk << 5) + (lq << 3)];
          acc[mi] = MFMA(af, bf, acc[mi]);
        }
      }
    }
    // transpose epilogue: RV[it][dd][i_local]; rows i>=196 are exact zeros (Ks pad)
#pragma unroll
    for (int mi = 0; mi < 4; mi++)
#pragma unroll
      for (int r = 0; r < 4; r++)
        RV[it][(w << 4) + lm][(mi << 4) + (lq << 2) + r] = f2bf(acc[mi][r]);
  }

  // ---- phase 2: left = relu(-0.125*q@k^T); out1 += wc * left @ RV
  size_t lbase = (size_t)bch * (196 * 196);
  for (int it = 0; it < 4; it++) {
    int i0 = it << 6;
    __syncthreads();  // phase1 readers of Qs done / prev-it qf loads done
    stage64(xq + (size_t)(b * 196 + i0) * 512 + (h << 6), 512, Qs, tid, 64);  // garbage tail masked
    __syncthreads();
    bf16x8 qf[4][2];
#pragma unroll
    for (int mi = 0; mi < 4; mi++)
#pragma unroll
      for (int kk = 0; kk < 2; kk++)
        qf[mi][kk] = *(const bf16x8*)&Qs[(mi << 4) + lm][(kk << 5) + (lq << 3)];
    f32x4 acc[4] = {};
    for (int jt = 0; jt < 4; jt++) {
      int j0 = jt << 6;
      __syncthreads();  // prev stage1/stage2 done with Ks/Ss
      stage64(aq + (size_t)(c * 196 + j0) * 512 + (h << 6), 512, Ks, tid, 64);  // garbage tail: Ss cols x RV zeros
      __syncthreads();
      f32x4 s[4] = {};
#pragma unroll
      for (int kk = 0; kk < 2; kk++) {
        bf16x8 bf = *(const bf16x8*)&Ks[(w << 4) + lm][(kk << 5) + (lq << 3)];
#pragma unroll
        for (int mi = 0; mi < 4; mi++) s[mi] = MFMA(qf[mi][kk], bf, s[mi]);
      }
      int jl = (w << 4) + lm;
      bool jok = (j0 + jl < 196);
#pragma unroll
      for (int mi = 0; mi < 4; mi++)
#pragma unroll
        for (int r = 0; r < 4; r++) {
          float v = fmaxf(-0.125f * s[mi][r], 0.f);
          int il = (mi << 4) + (lq << 2) + r;
          Ss[il][jl] = f2bf(v);
          if (jok && i0 + il < 196)
            left[lbase + (size_t)(i0 + il) * 196 + (j0 + jl)] = v;
        }
      __syncthreads();
#pragma unroll
      for (int kk = 0; kk < 2; kk++) {
        bf16x8 bf = *(const bf16x8*)&RV[jt][(w << 4) + lm][(kk << 5) + (lq << 3)];
#pragma unroll
        for (int mi = 0; mi < 4; mi++) {
          bf16x8 af = *(const bf16x8*)&Ss[(mi << 4) + lm][(kk << 5) + (lq << 3)];
          acc[mi] = MFMA(af, bf, acc[mi]);
        }
      }
    }
    // weighted atomic accumulate into out1 (b,h,n,dd) flat
    int dd = (w << 4) + lm;
#pragma unroll
    for (int mi = 0; mi < 4; mi++)
#pragma unroll
      for (int r = 0; r < 4; r++) {
        int i = i0 + (mi << 4) + (lq << 2) + r;
        if (i < 196)
          atomicAdd(&out1[((size_t)bh * 196 + i) * 64 + dd], wc * acc[mi][r]);
      }
  }
}

// ---- final: out[1568,512] = out1(f32) @ WprojT^T + bproj ----
__global__ __launch_bounds__(256) void final_gemm(const float* __restrict__ A, const unsigned short* __restrict__ WT,
                                                  const float* __restrict__ bias, float* __restrict__ out) {
  __shared__ unsigned short As[64][72];
  __shared__ unsigned short Ws[64][72];
  int row0 = blockIdx.x << 6;
  int col0 = blockIdx.y << 6;
  int tid = threadIdx.x;
  int w = tid >> 6, lm = tid & 15, lq = (tid >> 4) & 3;
  f32x4 acc[4] = {};
  for (int k0 = 0; k0 < 512; k0 += 64) {
    __syncthreads();
    {  // convert-stage A (f32 -> bf16), zero rows >= 1568
      int r = tid >> 2, c0 = (tid & 3) << 4;
      float4 f0, f1, f2, f3;
      if (row0 + r < 1568) {
        const float* p = A + (size_t)(row0 + r) * 512 + k0 + c0;
        f0 = *(const float4*)p;       f1 = *(const float4*)(p + 4);
        f2 = *(const float4*)(p + 8); f3 = *(const float4*)(p + 12);
      } else {
        f0 = f1 = f2 = f3 = make_float4(0.f, 0.f, 0.f, 0.f);
      }
      unsigned short s[16] = {f2bf(f0.x), f2bf(f0.y), f2bf(f0.z), f2bf(f0.w),
                              f2bf(f1.x), f2bf(f1.y), f2bf(f1.z), f2bf(f1.w),
                              f2bf(f2.x), f2bf(f2.y), f2bf(f2.z), f2bf(f2.w),
                              f2bf(f3.x), f2bf(f3.y), f2bf(f3.z), f2bf(f3.w)};
      *(uint4*)&As[r][c0] = *(uint4*)s;
      *(uint4*)&As[r][c0 + 8] = *(uint4*)(s + 8);
    }
    stage64(WT + (size_t)col0 * 512 + k0, 512, Ws, tid, 64);
    __syncthreads();
#pragma unroll
    for (int kk = 0; kk < 2; kk++) {
      bf16x8 bf = *(const bf16x8*)&Ws[(w << 4) + lm][(kk << 5) + (lq << 3)];
#pragma unroll
      for (int mi = 0; mi < 4; mi++) {
        bf16x8 af = *(const bf16x8*)&As[(mi << 4) + lm][(kk << 5) + (lq << 3)];
        acc[mi] = MFMA(af, bf, acc[mi]);
      }
    }
  }
  int ncol = col0 + (w << 4) + lm;
  float bv = bias[ncol];
#pragma unroll
  for (int mi = 0; mi < 4; mi++)
#pragma unroll
    for (int r2 = 0; r2 < 4; r2++) {
      int row = row0 + (mi << 4) + (lq << 2) + r2;
      if (row < 1568) out[(size_t)row * 512 + ncol] = acc[mi][r2] + bv;
    }
}

extern "C" void kernel_launch(void* const* d_in, const int* in_sizes, int n_in,
                              void* d_out, int out_size, void* d_ws, size_t ws_size,
                              hipStream_t stream) {
  (void)in_sizes; (void)n_in; (void)out_size; (void)ws_size;
  const float* x       = (const float*)d_in[0];
  const float* anchors = (const float*)d_in[1];
  const float* weights = (const float*)d_in[2];
  const float* Wqk     = (const float*)d_in[3];
  const float* Wqk2    = (const float*)d_in[4];
  const float* Wv      = (const float*)d_in[5];
  const float* Wproj   = (const float*)d_in[6];
  const float* bproj   = (const float*)d_in[7];
  char* ws = (char*)d_ws;                     // 17,752,064 bytes used
  float* out  = (float*)d_out;
  float* left = out + 802816;
  float* out1 = (float*)(ws + OFF_OUT1);

  dim3 blk(256);
  hipMemsetAsync(out1, 0, 3211264, stream);   // async, graph-capture safe
  pre_kernel<<<dim3(2020), blk, 0, stream>>>(x, anchors, Wqk, Wqk2, Wv, Wproj, ws);
  proj5<<<dim3(31, 8, 5), blk, 0, stream>>>(ws);
  fused_attn<<<dim3(640), blk, 0, stream>>>(ws, weights, left, out1);
  final_gemm<<<dim3(25, 8), blk, 0, stream>>>(out1, (const unsigned short*)(ws + OFF_WPROJT), bproj, out);
}

// Round 5
// 235.541 us; speedup vs baseline: 1.1210x; 1.1210x over previous
//
#include <hip/hip_runtime.h>

// B=8, N=196, C=512, NC=10, H=8, HD=64, SCALE=0.125
//
// Pipeline (bf16 MFMA 16x16x32, fp32 accum), wide 128-tiles everywhere:
//   pre:    x,anchors -> bf16; Wqk,Wqk2,Wv,Wproj -> bf16 transposed [n][k]
//   proj5:  XQ,XQ2 (1568x512), AQ,AQ2 (1960x512), XVT[512][1664] = (x@Wv)^T
//   rv2:    wrvT[bch][dd][j(264pad)] = w[b,h,c] * (relu(+S*k2@q2^T) @ v)^T, j>=196 zeroed
//   attn:   left = relu(-S*q@k^T) -> d_out (fp32); out1 += left @ wrv (fp32 atomics)
//   final:  out = out1 @ Wproj + bproj
//
// ws layout (bytes), total 39,477,248:
#define OFF_XB     0u          // 1,605,632
#define OFF_AB     1605632u    // 2,007,040
#define OFF_WQKT   3612672u    // 524,288
#define OFF_WQK2T  4136960u
#define OFF_WVT    4661248u
#define OFF_WPROJT 5185536u
#define OFF_XQ     5709824u    // 1,605,632
#define OFF_XQ2    7315456u
#define OFF_AQ     8921088u    // 2,007,040
#define OFF_AQ2    10928128u
#define OFF_XVT    12935168u   // 512*1664*2 = 1,703,936
#define OFF_WRVT   14639104u   // 640*64*264*2 = 21,626,880
#define OFF_OUT1   36265984u   // 1568*512*4 = 3,211,264

typedef __attribute__((ext_vector_type(8))) short bf16x8;
typedef __attribute__((ext_vector_type(4))) float f32x4;
#define MFMA(a, b, c) __builtin_amdgcn_mfma_f32_16x16x32_bf16((a), (b), (c), 0, 0, 0)

__device__ __forceinline__ unsigned short f2bf(float x) {
  unsigned u = __builtin_bit_cast(unsigned, x);
  u += 0x7fffu + ((u >> 16) & 1u);
  return (unsigned short)(u >> 16);
}

__device__ __forceinline__ void gl_lds16(const void* g, void* l) {
  __builtin_amdgcn_global_load_lds(
      (const __attribute__((address_space(1))) unsigned int*)g,
      (__attribute__((address_space(3))) unsigned int*)l, 16, 0, 0);
}

// 128 rows x 64 cols bf16 -> LDS [128][72] (144B rows = 9 x 16B chunks).
// Unconditional: overreads/garbage are masked algebraically downstream.
__device__ __forceinline__ void stage128(const unsigned short* g0, int stride,
                                         unsigned short (*T)[72], int tid) {
  char* base = (char*)&T[0][0];
  int wv = tid >> 6;
#pragma unroll
  for (int i = 0; i < 4; i++) {
    int k = i * 256 + tid;
    int r = k / 9, c = k - r * 9;
    gl_lds16(g0 + (size_t)r * stride + (c << 3), base + (((i << 2) + wv) << 10));
  }
  if (tid < 128) {
    int k = 1024 + tid;
    int r = k / 9, c = k - r * 9;
    gl_lds16(g0 + (size_t)r * stride + (c << 3), base + ((16 + wv) << 10));
  }
}

// 64 rows x 128 cols bf16 -> LDS [64][136] (272B rows = 17 x 16B chunks; chunk 16
// fills the pad with in-bounds garbage, never read).
__device__ __forceinline__ void stage64x128(const unsigned short* g0, int stride,
                                            unsigned short (*T)[136], int tid) {
  char* base = (char*)&T[0][0];
  int wv = tid >> 6;
#pragma unroll
  for (int i = 0; i < 4; i++) {
    int k = i * 256 + tid;
    int r = k / 17, c = k - r * 17;
    gl_lds16(g0 + (size_t)r * stride + (c << 3), base + (((i << 2) + wv) << 10));
  }
  if (tid < 64) {
    int k = 1024 + tid;
    int r = k / 17, c = k - r * 17;
    gl_lds16(g0 + (size_t)r * stride + (c << 3), base + (16 << 10));
  }
}

// 64 rows x 64 cols bf16 -> LDS [64][72] (used by final_gemm's W staging).
__device__ __forceinline__ void stage64(const unsigned short* g0, int stride,
                                        unsigned short (*T)[72], int tid) {
  int wv = tid >> 6;
  char* base = (char*)&T[0][0];
#pragma unroll
  for (int i = 0; i < 2; i++) {
    int k = i * 256 + tid;
    int r = k / 9, c = k - r * 9;
    gl_lds16(g0 + (size_t)r * stride + (c << 3), base + (((i << 2) + wv) << 10));
  }
  if (tid < 64) {
    int k = 512 + tid;
    int r = k / 9, c = k - r * 9;
    gl_lds16(g0 + (size_t)r * stride + (c << 3), base + 8192);
  }
}

// ---- pre: bf16 conversions + W transposes ----
__global__ __launch_bounds__(256) void pre_kernel(const float* __restrict__ x, const float* __restrict__ anchors,
                                                  const float* __restrict__ Wqk, const float* __restrict__ Wqk2,
                                                  const float* __restrict__ Wv, const float* __restrict__ Wproj,
                                                  char* __restrict__ ws) {
  int tid = threadIdx.x;
  if (blockIdx.x < 1764) {  // convert x (802816) + anchors (1003520) -> XB/AB (contiguous)
    int base = blockIdx.x * 1024 + (tid << 2);
    float4 f = (base < 802816) ? *(const float4*)(x + base)
                               : *(const float4*)(anchors + (base - 802816));
    unsigned short s[4] = {f2bf(f.x), f2bf(f.y), f2bf(f.z), f2bf(f.w)};
    *(uint2*)((unsigned short*)(ws + OFF_XB) + base) = *(uint2*)s;
    return;
  }
  __shared__ unsigned short Ls[64][72];
  int idx = blockIdx.x - 1764;
  int wsel = idx >> 6, t = idx & 63;
  int k0 = (t >> 3) << 6, n0 = (t & 7) << 6;
  const float* W;
  unsigned short* WT;
  switch (wsel) {
    case 0:  W = Wqk;   WT = (unsigned short*)(ws + OFF_WQKT);   break;
    case 1:  W = Wqk2;  WT = (unsigned short*)(ws + OFF_WQK2T);  break;
    case 2:  W = Wv;    WT = (unsigned short*)(ws + OFF_WVT);    break;
    default: W = Wproj; WT = (unsigned short*)(ws + OFF_WPROJT); break;
  }
  {
    int r = tid >> 2, seg = (tid & 3) << 4;
    const float* p = W + (size_t)(k0 + r) * 512 + n0 + seg;
    float4 f0 = *(const float4*)p, f1 = *(const float4*)(p + 4);
    float4 f2 = *(const float4*)(p + 8), f3 = *(const float4*)(p + 12);
    unsigned short s[16] = {f2bf(f0.x), f2bf(f0.y), f2bf(f0.z), f2bf(f0.w),
                            f2bf(f1.x), f2bf(f1.y), f2bf(f1.z), f2bf(f1.w),
                            f2bf(f2.x), f2bf(f2.y), f2bf(f2.z), f2bf(f2.w),
                            f2bf(f3.x), f2bf(f3.y), f2bf(f3.z), f2bf(f3.w)};
    *(uint4*)&Ls[r][seg] = *(uint4*)s;
    *(uint4*)&Ls[r][seg + 8] = *(uint4*)(s + 8);
  }
  __syncthreads();
  {
    int r = tid >> 2, seg = (tid & 3) << 4;
    unsigned short s[16];
#pragma unroll
    for (int u = 0; u < 16; u++) s[u] = Ls[seg + u][r];
    unsigned short* dst = WT + (size_t)(n0 + r) * 512 + k0 + seg;
    *(uint4*)dst = *(uint4*)s;
    *(uint4*)(dst + 8) = *(uint4*)(s + 8);
  }
}

// ---- proj5: 128x128-tile bf16 GEMMs ----
// z=0: XQ = XB@WqkT^T   z=1: XQ2 = XB@Wqk2T^T   z=2: AQ   z=3: AQ2
// z=4: XVT[512][1664] = WVT @ XB^T  (A=WVT rows=out rows, B=XB rows=tokens=out cols)
__global__ __launch_bounds__(256) void proj5(char* __restrict__ ws) {
  __shared__ unsigned short As[128][72];
  __shared__ unsigned short Bsh[128][72];
  const unsigned short* A;
  const unsigned short* Bp;
  unsigned short* O;
  int M, ostride, row0, col0;
  int z = blockIdx.z;
  if (z < 4) {
    row0 = blockIdx.x << 7;
    col0 = blockIdx.y << 7;
    ostride = 512;
    if (z < 2) { A = (const unsigned short*)(ws + OFF_XB); M = 1568; if (blockIdx.x >= 13) return; }
    else       { A = (const unsigned short*)(ws + OFF_AB); M = 1960; }
    Bp = (const unsigned short*)(ws + ((z & 1) ? OFF_WQK2T : OFF_WQKT));
    O  = (unsigned short*)(ws + (z == 0 ? OFF_XQ : z == 1 ? OFF_XQ2 : z == 2 ? OFF_AQ : OFF_AQ2));
  } else {
    if (blockIdx.x >= 13) return;
    row0 = blockIdx.y << 7;           // 0..384 over 512 rows
    col0 = blockIdx.x << 7;           // 0..1536 over 1664 cols (tokens)
    A = (const unsigned short*)(ws + OFF_WVT);
    Bp = (const unsigned short*)(ws + OFF_XB);
    O = (unsigned short*)(ws + OFF_XVT);
    M = 512; ostride = 1664;
  }
  int tid = threadIdx.x;
  int w = tid >> 6, lm = tid & 15, lq = (tid >> 4) & 3;
  int h1 = w & 1, h2 = w >> 1;
  f32x4 acc[4][4] = {};
  for (int k0 = 0; k0 < 512; k0 += 64) {
    __syncthreads();
    stage128(A + (size_t)row0 * 512 + k0, 512, As, tid);
    stage128(Bp + (size_t)col0 * 512 + k0, 512, Bsh, tid);
    __syncthreads();
#pragma unroll
    for (int kk = 0; kk < 2; kk++) {
      bf16x8 bfr[4];
#pragma unroll
      for (int ni = 0; ni < 4; ni++)
        bfr[ni] = *(const bf16x8*)&Bsh[(h2 << 6) + (ni << 4) + lm][(kk << 5) + (lq << 3)];
#pragma unroll
      for (int mi = 0; mi < 4; mi++) {
        bf16x8 afr = *(const bf16x8*)&As[(h1 << 6) + (mi << 4) + lm][(kk << 5) + (lq << 3)];
#pragma unroll
        for (int ni = 0; ni < 4; ni++) acc[mi][ni] = MFMA(afr, bfr[ni], acc[mi][ni]);
      }
    }
  }
#pragma unroll
  for (int mi = 0; mi < 4; mi++)
#pragma unroll
    for (int r = 0; r < 4; r++) {
      int row = row0 + (h1 << 6) + (mi << 4) + (lq << 2) + r;
      if (row < M) {
#pragma unroll
        for (int ni = 0; ni < 4; ni++) {
          int col = col0 + (h2 << 6) + (ni << 4) + lm;
          O[(size_t)row * ostride + col] = f2bf(acc[mi][ni][r]);
        }
      }
    }
}

// ---- rv2: wrvT[bch][dd][jpad264] = w * (relu(0.125*k2@q2^T) @ v)^T, j>=196 -> 0 ----
__global__ __launch_bounds__(256) void rv2(char* __restrict__ ws, const float* __restrict__ weights) {
  const unsigned short* xq2 = (const unsigned short*)(ws + OFF_XQ2);
  const unsigned short* aq2 = (const unsigned short*)(ws + OFF_AQ2);
  const unsigned short* xvt = (const unsigned short*)(ws + OFF_XVT);
  unsigned short* wrvt      = (unsigned short*)(ws + OFF_WRVT);
  __shared__ unsigned short Bs[128][72];
  __shared__ unsigned short Ss[128][136];
  __shared__ unsigned short Vt[64][136];
  int jblk = blockIdx.x, bch = blockIdx.y;
  int h = bch & 7, bc = bch >> 3;
  int c = bc % 10, b = bc / 10;
  int bh = b * 8 + h;
  int tid = threadIdx.x;
  int w = tid >> 6, lm = tid & 15, lq = (tid >> 4) & 3;
  int h1 = w & 1, h2 = w >> 1;
  float wc = weights[bh * 10 + c];

  stage128(aq2 + (size_t)(c * 196 + jblk * 128) * 512 + (h << 6), 512, Bs, tid);
  __syncthreads();
  bf16x8 af[4][2];
#pragma unroll
  for (int mi = 0; mi < 4; mi++)
#pragma unroll
    for (int kk = 0; kk < 2; kk++)
      af[mi][kk] = *(const bf16x8*)&Bs[(h1 << 6) + (mi << 4) + lm][(kk << 5) + (lq << 3)];

  f32x4 acc[4][2] = {};
  for (int mt = 0; mt < 2; mt++) {
    __syncthreads();  // frags loaded / prev S-MFMA done with Bs; prev PV done with Vt
    stage128(xq2 + (size_t)(b * 196 + mt * 128) * 512 + (h << 6), 512, Bs, tid);
    stage64x128(xvt + (size_t)(h << 6) * 1664 + b * 196 + mt * 128, 1664, Vt, tid);
    __syncthreads();
    f32x4 s[4][4] = {};
#pragma unroll
    for (int kk = 0; kk < 2; kk++) {
      bf16x8 bfr[4];
#pragma unroll
      for (int ni = 0; ni < 4; ni++)
        bfr[ni] = *(const bf16x8*)&Bs[(h2 << 6) + (ni << 4) + lm][(kk << 5) + (lq << 3)];
#pragma unroll
      for (int mi = 0; mi < 4; mi++)
#pragma unroll
        for (int ni = 0; ni < 4; ni++) s[mi][ni] = MFMA(af[mi][kk], bfr[ni], s[mi][ni]);
    }
    // S2 -> Ss (bf16), zero cols m>=196 (kills garbage x-token tails)
#pragma unroll
    for (int ni = 0; ni < 4; ni++) {
      int ml = (h2 << 6) + (ni << 4) + lm;
      bool ok = (mt * 128 + ml) < 196;
#pragma unroll
      for (int mi = 0; mi < 4; mi++)
#pragma unroll
        for (int r = 0; r < 4; r++) {
          float v = ok ? fmaxf(0.125f * s[mi][ni][r], 0.f) : 0.f;
          Ss[(h1 << 6) + (mi << 4) + (lq << 2) + r][ml] = f2bf(v);
        }
    }
    __syncthreads();
#pragma unroll
    for (int kk = 0; kk < 4; kk++) {
      bf16x8 bfr[2];
#pragma unroll
      for (int ni = 0; ni < 2; ni++)
        bfr[ni] = *(const bf16x8*)&Vt[(h2 << 5) + (ni << 4) + lm][(kk << 5) + (lq << 3)];
#pragma unroll
      for (int mi = 0; mi < 4; mi++) {
        bf16x8 afr = *(const bf16x8*)&Ss[(h1 << 6) + (mi << 4) + lm][(kk << 5) + (lq << 3)];
#pragma unroll
        for (int ni = 0; ni < 2; ni++) acc[mi][ni] = MFMA(afr, bfr[ni], acc[mi][ni]);
      }
    }
  }
  __syncthreads();  // all PV reads of Ss done -> reuse as transpose buffer [64 dd][136]
#pragma unroll
  for (int mi = 0; mi < 4; mi++)
#pragma unroll
    for (int ni = 0; ni < 2; ni++)
#pragma unroll
      for (int r = 0; r < 4; r++)
        Ss[(h2 << 5) + (ni << 4) + lm][(h1 << 6) + (mi << 4) + (lq << 2) + r] =
            f2bf(wc * acc[mi][ni][r]);
  __syncthreads();
  {
    int dd = tid >> 2, seg = (tid & 3) << 5;
    unsigned short vbuf[32];
#pragma unroll
    for (int u = 0; u < 32; u++) {
      int j = jblk * 128 + seg + u;
      vbuf[u] = (j < 196) ? Ss[dd][seg + u] : (unsigned short)0;
    }
    unsigned short* dst = wrvt + ((size_t)bch * 64 + dd) * 264 + jblk * 128 + seg;
#pragma unroll
    for (int u = 0; u < 4; u++) *(uint4*)(dst + (u << 3)) = *(uint4*)&vbuf[u << 3];
  }
}

// ---- attn_left: left = relu(-0.125*q@k^T) -> d_out; out1 += left @ wrv (atomics) ----
__global__ __launch_bounds__(256) void attn_left(char* __restrict__ ws, float* __restrict__ left,
                                                 float* __restrict__ out1) {
  const unsigned short* xq   = (const unsigned short*)(ws + OFF_XQ);
  const unsigned short* aq   = (const unsigned short*)(ws + OFF_AQ);
  const unsigned short* wrvt = (const unsigned short*)(ws + OFF_WRVT);
  __shared__ unsigned short Bs[128][72];
  __shared__ unsigned short Ss[128][136];
  __shared__ unsigned short Rt[64][136];
  int iblk = blockIdx.x, bch = blockIdx.y;
  int h = bch & 7, bc = bch >> 3;
  int c = bc % 10, b = bc / 10;
  int bh = b * 8 + h;
  int tid = threadIdx.x;
  int w = tid >> 6, lm = tid & 15, lq = (tid >> 4) & 3;
  int h1 = w & 1, h2 = w >> 1;

  stage128(xq + (size_t)(b * 196 + iblk * 128) * 512 + (h << 6), 512, Bs, tid);
  __syncthreads();
  bf16x8 qf[4][2];
#pragma unroll
  for (int mi = 0; mi < 4; mi++)
#pragma unroll
    for (int kk = 0; kk < 2; kk++)
      qf[mi][kk] = *(const bf16x8*)&Bs[(h1 << 6) + (mi << 4) + lm][(kk << 5) + (lq << 3)];

  f32x4 acc[4][2] = {};
  size_t lbase = (size_t)bch * (196 * 196);
  for (int jt = 0; jt < 2; jt++) {
    __syncthreads();  // frags loaded / prev PV done with Bs, Rt, Ss
    stage128(aq + (size_t)(c * 196 + jt * 128) * 512 + (h << 6), 512, Bs, tid);
    stage64x128(wrvt + (size_t)bch * 64 * 264 + jt * 128, 264, Rt, tid);
    __syncthreads();
    f32x4 s[4][4] = {};
#pragma unroll
    for (int kk = 0; kk < 2; kk++) {
      bf16x8 bfr[4];
#pragma unroll
      for (int ni = 0; ni < 4; ni++)
        bfr[ni] = *(const bf16x8*)&Bs[(h2 << 6) + (ni << 4) + lm][(kk << 5) + (lq << 3)];
#pragma unroll
      for (int mi = 0; mi < 4; mi++)
#pragma unroll
        for (int ni = 0; ni < 4; ni++) s[mi][ni] = MFMA(qf[mi][kk], bfr[ni], s[mi][ni]);
    }
    // relu(-S) -> left (fp32, masked) + Ss (bf16; garbage cols j>=196 zeroed by wrvT pad)
#pragma unroll
    for (int mi = 0; mi < 4; mi++)
#pragma unroll
      for (int r = 0; r < 4; r++) {
        int il = (h1 << 6) + (mi << 4) + (lq << 2) + r;
        int i = iblk * 128 + il;
        bool iok = i < 196;
#pragma unroll
        for (int ni = 0; ni < 4; ni++) {
          int jl = (h2 << 6) + (ni << 4) + lm;
          float v = fmaxf(-0.125f * s[mi][ni][r], 0.f);
          Ss[il][jl] = f2bf(v);
          int j = jt * 128 + jl;
          if (iok && j < 196) left[lbase + (size_t)i * 196 + j] = v;
        }
      }
    __syncthreads();
#pragma unroll
    for (int kk = 0; kk < 4; kk++) {
      bf16x8 bfr[2];
#pragma unroll
      for (int ni = 0; ni < 2; ni++)
        bfr[ni] = *(const bf16x8*)&Rt[(h2 << 5) + (ni << 4) + lm][(kk << 5) + (lq << 3)];
#pragma unroll
      for (int mi = 0; mi < 4; mi++) {
        bf16x8 afr = *(const bf16x8*)&Ss[(h1 << 6) + (mi << 4) + lm][(kk << 5) + (lq << 3)];
#pragma unroll
        for (int ni = 0; ni < 2; ni++) acc[mi][ni] = MFMA(afr, bfr[ni], acc[mi][ni]);
      }
    }
  }
#pragma unroll
  for (int mi = 0; mi < 4; mi++)
#pragma unroll
    for (int r = 0; r < 4; r++) {
      int i = iblk * 128 + (h1 << 6) + (mi << 4) + (lq << 2) + r;
      if (i < 196) {
#pragma unroll
        for (int ni = 0; ni < 2; ni++) {
          int dd = (h2 << 5) + (ni << 4) + lm;
          atomicAdd(&out1[((size_t)bh * 196 + i) * 64 + dd], acc[mi][ni][r]);
        }
      }
    }
}

// ---- final: out[1568,512] = out1(f32) @ WprojT^T + bproj ----
__global__ __launch_bounds__(256) void final_gemm(const float* __restrict__ A, const unsigned short* __restrict__ WT,
                                                  const float* __restrict__ bias, float* __restrict__ out) {
  __shared__ unsigned short As[64][72];
  __shared__ unsigned short Ws[64][72];
  int row0 = blockIdx.x << 6;
  int col0 = blockIdx.y << 6;
  int tid = threadIdx.x;
  int w = tid >> 6, lm = tid & 15, lq = (tid >> 4) & 3;
  f32x4 acc[4] = {};
  for (int k0 = 0; k0 < 512; k0 += 64) {
    __syncthreads();
    {  // convert-stage A (f32 -> bf16), zero rows >= 1568
      int r = tid >> 2, c0 = (tid & 3) << 4;
      float4 f0, f1, f2, f3;
      if (row0 + r < 1568) {
        const float* p = A + (size_t)(row0 + r) * 512 + k0 + c0;
        f0 = *(const float4*)p;       f1 = *(const float4*)(p + 4);
        f2 = *(const float4*)(p + 8); f3 = *(const float4*)(p + 12);
      } else {
        f0 = f1 = f2 = f3 = make_float4(0.f, 0.f, 0.f, 0.f);
      }
      unsigned short s[16] = {f2bf(f0.x), f2bf(f0.y), f2bf(f0.z), f2bf(f0.w),
                              f2bf(f1.x), f2bf(f1.y), f2bf(f1.z), f2bf(f1.w),
                              f2bf(f2.x), f2bf(f2.y), f2bf(f2.z), f2bf(f2.w),
                              f2bf(f3.x), f2bf(f3.y), f2bf(f3.z), f2bf(f3.w)};
      *(uint4*)&As[r][c0] = *(uint4*)s;
      *(uint4*)&As[r][c0 + 8] = *(uint4*)(s + 8);
    }
    stage64(WT + (size_t)col0 * 512 + k0, 512, Ws, tid);
    __syncthreads();
#pragma unroll
    for (int kk = 0; kk < 2; kk++) {
      bf16x8 bf = *(const bf16x8*)&Ws[(w << 4) + lm][(kk << 5) + (lq << 3)];
#pragma unroll
      for (int mi = 0; mi < 4; mi++) {
        bf16x8 af = *(const bf16x8*)&As[(mi << 4) + lm][(kk << 5) + (lq << 3)];
        acc[mi] = MFMA(af, bf, acc[mi]);
      }
    }
  }
  int ncol = col0 + (w << 4) + lm;
  float bv = bias[ncol];
#pragma unroll
  for (int mi = 0; mi < 4; mi++)
#pragma unroll
    for (int r2 = 0; r2 < 4; r2++) {
      int row = row0 + (mi << 4) + (lq << 2) + r2;
      if (row < 1568) out[(size_t)row * 512 + ncol] = acc[mi][r2] + bv;
    }
}

extern "C" void kernel_launch(void* const* d_in, const int* in_sizes, int n_in,
                              void* d_out, int out_size, void* d_ws, size_t ws_size,
                              hipStream_t stream) {
  (void)in_sizes; (void)n_in; (void)out_size; (void)ws_size;
  const float* x       = (const float*)d_in[0];
  const float* anchors = (const float*)d_in[1];
  const float* weights = (const float*)d_in[2];
  const float* Wqk     = (const float*)d_in[3];
  const float* Wqk2    = (const float*)d_in[4];
  const float* Wv      = (const float*)d_in[5];
  const float* Wproj   = (const float*)d_in[6];
  const float* bproj   = (const float*)d_in[7];
  char* ws = (char*)d_ws;                     // 39,477,248 bytes used
  float* out  = (float*)d_out;
  float* left = out + 802816;
  float* out1 = (float*)(ws + OFF_OUT1);

  dim3 blk(256);
  hipMemsetAsync(out1, 0, 3211264, stream);
  pre_kernel<<<dim3(2020), blk, 0, stream>>>(x, anchors, Wqk, Wqk2, Wv, Wproj, ws);
  proj5<<<dim3(16, 4, 5), blk, 0, stream>>>(ws);
  rv2<<<dim3(2, 640), blk, 0, stream>>>(ws, weights);
  attn_left<<<dim3(2, 640), blk, 0, stream>>>(ws, left, out1);
  final_gemm<<<dim3(25, 8), blk, 0, stream>>>(out1, (const unsigned short*)(ws + OFF_WPROJT), bproj, out);
}